// Round 13
// baseline (276.089 us; speedup 1.0000x reference)
//
#include <hip/hip_runtime.h>
#include <math.h>

#define BATCH   256
#define IN_F    2048
#define OUT_F   256
#define NCOL    2048    /* OUT_F*KD */
#define OSTRIDE 2304    /* IN_F + OUT_F */
#define LOG2E   1.4426950408889634f

typedef float    f32x4  __attribute__((ext_vector_type(4)));
typedef short    bf16x8 __attribute__((ext_vector_type(8)));
typedef _Float16 h16x2  __attribute__((ext_vector_type(2)));
typedef __fp16   fp16x2 __attribute__((ext_vector_type(2)));
typedef unsigned short u16;
typedef unsigned int   u32;

// ws layout:
//   [0, 1MB)   Mh f16 [256 o][256 j][8 k]
//   [16,24MB)  Wt bf16 tiled [nt(128)][kc(256)][n16(16)][8]
//   [64,65MB)  Xb bf16 tiled [rt(16)][kc(256)][r16(16)][8] (pre *log2e)
#define WT_BASE   (16u << 20)
#define XB_BASE   (64u << 20)

__device__ __forceinline__ u16 f2bf(float f) {
    unsigned u = __builtin_bit_cast(unsigned, f);
    u += 0x7fff + ((u >> 16) & 1);              // RNE
    return (u16)(u >> 16);
}

__device__ __forceinline__ float exp2_fast(float x) {
#if __has_builtin(__builtin_amdgcn_exp2f)
    return __builtin_amdgcn_exp2f(x);
#else
    float r; asm("v_exp_f32 %0, %1" : "=v"(r) : "v"(x)); return r;
#endif
}

__device__ __forceinline__ float hsum_neg(h16x2 s) {
#if __has_builtin(__builtin_amdgcn_fdot2)
    const h16x2 n1 = {(_Float16)-1.0f, (_Float16)-1.0f};
    return __builtin_amdgcn_fdot2(s, n1, 0.0f, false);
#else
    return -((float)s[0] + (float)s[1]);
#endif
}

// ---------------------------------------------------------------------------
// Prep (R12 body, rep-looped for diagnosis).
// ---------------------------------------------------------------------------
__global__ __launch_bounds__(256)
void k_prep(const float* __restrict__ X0, const float* __restrict__ T0,
            u16* __restrict__ Wt0, u16* __restrict__ Xb0,
            float* __restrict__ out0, int reps, size_t zoff) {
    const int b = blockIdx.x, t = threadIdx.x;
    for (int rep = 0; rep < reps; ++rep) {
        const float* X = X0 + zoff * rep;       // zoff==0 at runtime, opaque
        const float* T = T0 + zoff * rep;
        u16* Wt = Wt0 + zoff * rep;
        u16* Xb = Xb0 + zoff * rep;
        float* out = out0 + zoff * rep;
        if (b < 128) {
            const int np = (b & 3) * 256 + t;
            const int n  = np * 2;
            const int kg = b >> 2;
            const int nt = n >> 4, n16 = n & 15;
#pragma unroll
            for (int kc = 0; kc < 8; ++kc) {
                const int kb = kg * 64 + kc * 8;
                u16 h0[8], h1[8];
#pragma unroll
                for (int r = 0; r < 8; ++r) {
                    float2 v = *(const float2*)(T + (size_t)(kb + r) * NCOL + n);
                    h0[r] = f2bf(v.x);
                    h1[r] = f2bf(v.y);
                }
                u16* dst = Wt + ((size_t)(nt * 256 + kg * 8 + kc) * 16 + n16) * 8;
                *(float4*)dst       = *(float4*)h0;
                *(float4*)(dst + 8) = *(float4*)h1;
            }
        } else {
            const int g   = b - 128;
            const int rt  = g >> 4;
            const int kc  = (g & 15) * 16 + (t & 15);
            const int r16 = t >> 4;
            const int row = rt * 16 + r16;
            const float* src = X + (size_t)row * IN_F + kc * 8;
            float4 v0 = *(const float4*)src;
            float4 v1 = *(const float4*)(src + 4);
            u16 h[8] = {f2bf(v0.x * LOG2E), f2bf(v0.y * LOG2E),
                        f2bf(v0.z * LOG2E), f2bf(v0.w * LOG2E),
                        f2bf(v1.x * LOG2E), f2bf(v1.y * LOG2E),
                        f2bf(v1.z * LOG2E), f2bf(v1.w * LOG2E)};
            *(float4*)(Xb + ((size_t)(rt * 256 + kc) * 16 + r16) * 8) = *(float4*)h;
            float* od = out + (size_t)row * OSTRIDE + kc * 8;
            *(float4*)od       = v0;
            *(float4*)(od + 4) = v1;
        }
    }
}

// ---------------------------------------------------------------------------
// GEMM (R12 body, rep-looped). Per-XCD working set 16MB >> 4MB L2, so every
// rep is L2-cold like the single-shot run.
// ---------------------------------------------------------------------------
__global__ __launch_bounds__(512, 4)
void k_gemm(const u16* __restrict__ Xb0, const u16* __restrict__ Wt0,
            u16* __restrict__ Mh0, int reps, size_t zoff) {
    __shared__ float L[8][32][33];
    const int t = threadIdx.x, l = t & 63, kcw = t >> 6;
    const int bid = blockIdx.x;
    const int R = bid >> 6;
    const int C = bid & 63;
    const int lo = (l >> 4) * 128 + (l & 15) * 8;
    const int lq = l >> 4, lm = l & 15;

    for (int rep = 0; rep < reps; ++rep) {
        const u16* Xb = Xb0 + zoff * rep;
        const u16* Wt = Wt0 + zoff * rep;
        u16* Mh = Mh0 + zoff * rep;

        const u16* ap0 = Xb + (size_t)(R * 2) * 32768 + kcw * 4096 + lo;
        const u16* ap1 = ap0 + 32768;
        const u16* bp0 = Wt + (size_t)(C * 2) * 32768 + kcw * 4096 + lo;
        const u16* bp1 = bp0 + 32768;

        f32x4 c00 = {0.f,0.f,0.f,0.f}, c01 = {0.f,0.f,0.f,0.f};
        f32x4 c10 = {0.f,0.f,0.f,0.f}, c11 = {0.f,0.f,0.f,0.f};

#pragma unroll 8
        for (int s = 0; s < 8; ++s) {
            bf16x8 a0 = *(const bf16x8*)(ap0 + s * 512);
            bf16x8 a1 = *(const bf16x8*)(ap1 + s * 512);
            bf16x8 b0 = *(const bf16x8*)(bp0 + s * 512);
            bf16x8 b1 = *(const bf16x8*)(bp1 + s * 512);
            c00 = __builtin_amdgcn_mfma_f32_16x16x32_bf16(a0, b0, c00, 0, 0, 0);
            c01 = __builtin_amdgcn_mfma_f32_16x16x32_bf16(a0, b1, c01, 0, 0, 0);
            c10 = __builtin_amdgcn_mfma_f32_16x16x32_bf16(a1, b0, c10, 0, 0, 0);
            c11 = __builtin_amdgcn_mfma_f32_16x16x32_bf16(a1, b1, c11, 0, 0, 0);
        }

#define PUT(acc, qi, qj) do { \
        _Pragma("unroll") \
        for (int r = 0; r < 4; ++r) \
            L[kcw][(qj) * 16 + lm][(qi) * 16 + lq * 4 + r] = acc[r]; \
    } while (0)
        PUT(c00, 0, 0); PUT(c01, 0, 1); PUT(c10, 1, 0); PUT(c11, 1, 1);
#undef PUT
        __syncthreads();

        if (t < 256) {
            const int o2 = t >> 6;
            const int jl = (t & 63) >> 1;
            const int k0 = (t & 1) * 4;
            float v[4];
#pragma unroll
            for (int i = 0; i < 4; ++i) {
                const int c = o2 * 8 + k0 + i;
                float s0 = (L[0][c][jl] + L[1][c][jl]) + (L[2][c][jl] + L[3][c][jl]);
                float s1 = (L[4][c][jl] + L[5][c][jl]) + (L[6][c][jl] + L[7][c][jl]);
                v[i] = s0 + s1;
            }
            fp16x2 p0 = __builtin_amdgcn_cvt_pkrtz(v[0], v[1]);
            fp16x2 p1 = __builtin_amdgcn_cvt_pkrtz(v[2], v[3]);
            uint2 pk = {__builtin_bit_cast(u32, p0), __builtin_bit_cast(u32, p1)};
            *(uint2*)(Mh + ((size_t)(C * 4 + o2) * 256 + R * 32 + jl) * 8 + k0) = pk;
        }
        __syncthreads();   // protect L across reps
    }
}

// ---------------------------------------------------------------------------
// Pair (R12 j-blocked body, rep-looped).
// ---------------------------------------------------------------------------
__global__ __launch_bounds__(1024)
void k_pair(const u16* __restrict__ Mh0, float* __restrict__ out,
            int reps, size_t zoff) {
    __shared__ __align__(16) uint4 Msh[BATCH];    // 4 KB
    __shared__ float Ps[16][256];                 // 16 KB
    const int o = blockIdx.x, t = threadIdx.x;
    const int jg = t & 63, q = t >> 6;

    for (int rep = 0; rep < reps; ++rep) {
        const u16* Mh = Mh0 + zoff * rep;
        if (t < 256) Msh[t] = ((const uint4*)(Mh + (size_t)o * 2048))[t];
        __syncthreads();

        h16x2 m[4][4];
#pragma unroll
        for (int c = 0; c < 4; ++c) {
            uint4 mm = Msh[jg + 64 * c];
            m[c][0] = __builtin_bit_cast(h16x2, mm.x);
            m[c][1] = __builtin_bit_cast(h16x2, mm.y);
            m[c][2] = __builtin_bit_cast(h16x2, mm.z);
            m[c][3] = __builtin_bit_cast(h16x2, mm.w);
        }

        float acc[4] = {0.f, 0.f, 0.f, 0.f};
        const int i0 = q * 16;
#pragma unroll 2
        for (int ii = 0; ii < 16; ++ii) {
            uint4 uu = Msh[i0 + ii];              // broadcast ds_read_b128
            const h16x2 u0 = __builtin_bit_cast(h16x2, uu.x);
            const h16x2 u1 = __builtin_bit_cast(h16x2, uu.y);
            const h16x2 u2 = __builtin_bit_cast(h16x2, uu.z);
            const h16x2 u3 = __builtin_bit_cast(h16x2, uu.w);
#pragma unroll
            for (int c = 0; c < 4; ++c) {
                h16x2 d0 = u0 - m[c][0];
                h16x2 d1 = u1 - m[c][1];
                h16x2 d2 = u2 - m[c][2];
                h16x2 d3 = u3 - m[c][3];
                h16x2 e0 = __builtin_bit_cast(h16x2, __builtin_bit_cast(u32, d0) & 0x7fff7fffu);
                h16x2 e1 = __builtin_bit_cast(h16x2, __builtin_bit_cast(u32, d1) & 0x7fff7fffu);
                h16x2 e2 = __builtin_bit_cast(h16x2, __builtin_bit_cast(u32, d2) & 0x7fff7fffu);
                h16x2 e3 = __builtin_bit_cast(h16x2, __builtin_bit_cast(u32, d3) & 0x7fff7fffu);
                h16x2 s = (e0 + e1) + (e2 + e3);
                acc[c] += exp2_fast(hsum_neg(s));
            }
        }
#pragma unroll
        for (int c = 0; c < 4; ++c) Ps[q][jg + 64 * c] = acc[c];
        __syncthreads();

        if (t < 256) {
            float s = 0.f;
#pragma unroll
            for (int q2 = 0; q2 < 16; ++q2) s += Ps[q2][t];
            out[(size_t)t * OSTRIDE + IN_F + o] = s - 1.0f;
        }
        __syncthreads();   // protect Msh/Ps across reps
    }
}

extern "C" void kernel_launch(void* const* d_in, const int* in_sizes, int n_in,
                              void* d_out, int out_size, void* d_ws, size_t ws_size,
                              hipStream_t stream) {
    const float* x = (const float*)d_in[0];   // [256, 2048]
    const float* T = (const float*)d_in[1];   // [2048][2048] flattened
    float* out = (float*)d_out;               // [256, 2304]
    char* ws = (char*)d_ws;
    u16* Mh = (u16*)ws;
    u16* Wt = (u16*)(ws + WT_BASE);
    u16* Xb = (u16*)(ws + XB_BASE);
    const size_t zoff = (size_t)(in_sizes[0] - 524288);   // == 0, opaque

    k_prep<<<384, 256, 0, stream>>>(x, T, Wt, Xb, out, 16, zoff);
    k_gemm<<<512, 512, 0, stream>>>(Xb, Wt, Mh, 20, zoff);
    k_pair<<<256, 1024, 0, stream>>>(Mh, out, 16, zoff);
}

// Round 14
// 28.067 us; speedup vs baseline: 9.8369x; 9.8369x over previous
//
#include <hip/hip_runtime.h>
#include <math.h>

#define BATCH   256
#define IN_F    2048
#define OUT_F   256
#define NCOL    2048    /* OUT_F*KD */
#define OSTRIDE 2304    /* IN_F + OUT_F */
#define LOG2E   1.4426950408889634f

typedef float    f32x4  __attribute__((ext_vector_type(4)));
typedef short    bf16x8 __attribute__((ext_vector_type(8)));
typedef _Float16 h16x2  __attribute__((ext_vector_type(2)));
typedef __fp16   fp16x2 __attribute__((ext_vector_type(2)));
typedef unsigned short u16;
typedef unsigned int   u32;

// ws layout:
//   [0, 1MB)   Mh f16 [256 o][256 j][8 k]
//   [16,24MB)  Wt bf16 tiled [nt(128)][kc(256)][n16(16)][8]
//   [64,65MB)  Xb bf16 tiled [rt(16)][kc(256)][r16(16)][8] (pre *log2e)
#define WT_BASE   (16u << 20)
#define XB_BASE   (64u << 20)

__device__ __forceinline__ u16 f2bf(float f) {
    unsigned u = __builtin_bit_cast(unsigned, f);
    u += 0x7fff + ((u >> 16) & 1);              // RNE
    return (u16)(u >> 16);
}

__device__ __forceinline__ float exp2_fast(float x) {
#if __has_builtin(__builtin_amdgcn_exp2f)
    return __builtin_amdgcn_exp2f(x);
#else
    float r; asm("v_exp_f32 %0, %1" : "=v"(r) : "v"(x)); return r;
#endif
}

__device__ __forceinline__ float hsum_neg(h16x2 s) {
#if __has_builtin(__builtin_amdgcn_fdot2)
    const h16x2 n1 = {(_Float16)-1.0f, (_Float16)-1.0f};
    return __builtin_amdgcn_fdot2(s, n1, 0.0f, false);
#else
    return -((float)s[0] + (float)s[1]);
#endif
}

__device__ __forceinline__ float bperm(int srcLane, float v) {
    return __builtin_bit_cast(float,
        __builtin_amdgcn_ds_bpermute(srcLane * 4, __builtin_bit_cast(int, v)));
}

// ---------------------------------------------------------------------------
// Prep: blocks 0..127 = T transpose+convert; 128..383 = X convert + copy.
// (identical to R12)
// ---------------------------------------------------------------------------
__global__ __launch_bounds__(256)
void k_prep(const float* __restrict__ X, const float* __restrict__ T,
            u16* __restrict__ Wt, u16* __restrict__ Xb,
            float* __restrict__ out) {
    const int b = blockIdx.x, t = threadIdx.x;
    if (b < 128) {
        const int np = (b & 3) * 256 + t;
        const int n  = np * 2;
        const int kg = b >> 2;
        const int nt = n >> 4, n16 = n & 15;
#pragma unroll
        for (int kc = 0; kc < 8; ++kc) {
            const int kb = kg * 64 + kc * 8;
            u16 h0[8], h1[8];
#pragma unroll
            for (int r = 0; r < 8; ++r) {
                float2 v = *(const float2*)(T + (size_t)(kb + r) * NCOL + n);
                h0[r] = f2bf(v.x);
                h1[r] = f2bf(v.y);
            }
            u16* dst = Wt + ((size_t)(nt * 256 + kg * 8 + kc) * 16 + n16) * 8;
            *(float4*)dst       = *(float4*)h0;
            *(float4*)(dst + 8) = *(float4*)h1;
        }
    } else {
        const int g   = b - 128;
        const int rt  = g >> 4;
        const int kc  = (g & 15) * 16 + (t & 15);
        const int r16 = t >> 4;
        const int row = rt * 16 + r16;
        const float* src = X + (size_t)row * IN_F + kc * 8;
        float4 v0 = *(const float4*)src;
        float4 v1 = *(const float4*)(src + 4);
        u16 h[8] = {f2bf(v0.x * LOG2E), f2bf(v0.y * LOG2E),
                    f2bf(v0.z * LOG2E), f2bf(v0.w * LOG2E),
                    f2bf(v1.x * LOG2E), f2bf(v1.y * LOG2E),
                    f2bf(v1.z * LOG2E), f2bf(v1.w * LOG2E)};
        *(float4*)(Xb + ((size_t)(rt * 256 + kc) * 16 + r16) * 8) = *(float4*)h;
        float* od = out + (size_t)row * OSTRIDE + kc * 8;
        *(float4*)od       = v0;
        *(float4*)(od + 4) = v1;
    }
}

// ---------------------------------------------------------------------------
// MFMA GEMM (8-way in-block split-K). 512 blocks x 8 waves, 2 blocks/CU.
// (identical to R12)
// ---------------------------------------------------------------------------
__global__ __launch_bounds__(512, 4)
void k_gemm(const u16* __restrict__ Xb, const u16* __restrict__ Wt,
            u16* __restrict__ Mh) {
    __shared__ float L[8][32][33];     // 33.8 KB
    const int t = threadIdx.x, l = t & 63, kcw = t >> 6;
    const int bid = blockIdx.x;
    const int R = bid >> 6;            // 0..7
    const int C = bid & 63;            // 0..63

    const int lo = (l >> 4) * 128 + (l & 15) * 8;
    const u16* ap0 = Xb + (size_t)(R * 2) * 32768 + kcw * 4096 + lo;
    const u16* ap1 = ap0 + 32768;
    const u16* bp0 = Wt + (size_t)(C * 2) * 32768 + kcw * 4096 + lo;
    const u16* bp1 = bp0 + 32768;

    f32x4 c00 = {0.f,0.f,0.f,0.f}, c01 = {0.f,0.f,0.f,0.f};
    f32x4 c10 = {0.f,0.f,0.f,0.f}, c11 = {0.f,0.f,0.f,0.f};

#pragma unroll 8
    for (int s = 0; s < 8; ++s) {
        bf16x8 a0 = *(const bf16x8*)(ap0 + s * 512);
        bf16x8 a1 = *(const bf16x8*)(ap1 + s * 512);
        bf16x8 b0 = *(const bf16x8*)(bp0 + s * 512);
        bf16x8 b1 = *(const bf16x8*)(bp1 + s * 512);
        c00 = __builtin_amdgcn_mfma_f32_16x16x32_bf16(a0, b0, c00, 0, 0, 0);
        c01 = __builtin_amdgcn_mfma_f32_16x16x32_bf16(a0, b1, c01, 0, 0, 0);
        c10 = __builtin_amdgcn_mfma_f32_16x16x32_bf16(a1, b0, c10, 0, 0, 0);
        c11 = __builtin_amdgcn_mfma_f32_16x16x32_bf16(a1, b1, c11, 0, 0, 0);
    }

    const int lq = l >> 4, lm = l & 15;
#define PUT(acc, qi, qj) do { \
        _Pragma("unroll") \
        for (int r = 0; r < 4; ++r) \
            L[kcw][(qj) * 16 + lm][(qi) * 16 + lq * 4 + r] = acc[r]; \
    } while (0)
    PUT(c00, 0, 0); PUT(c01, 0, 1); PUT(c10, 1, 0); PUT(c11, 1, 1);
#undef PUT
    __syncthreads();

    if (t < 256) {
        const int o2 = t >> 6;             // 0..3
        const int jl = (t & 63) >> 1;      // 0..31
        const int k0 = (t & 1) * 4;        // 0 or 4
        float v[4];
#pragma unroll
        for (int i = 0; i < 4; ++i) {
            const int c = o2 * 8 + k0 + i;
            float s0 = (L[0][c][jl] + L[1][c][jl]) + (L[2][c][jl] + L[3][c][jl]);
            float s1 = (L[4][c][jl] + L[5][c][jl]) + (L[6][c][jl] + L[7][c][jl]);
            v[i] = s0 + s1;
        }
        fp16x2 p0 = __builtin_amdgcn_cvt_pkrtz(v[0], v[1]);
        fp16x2 p1 = __builtin_amdgcn_cvt_pkrtz(v[2], v[3]);
        uint2 pk = {__builtin_bit_cast(u32, p0), __builtin_bit_cast(u32, p1)};
        *(uint2*)(Mh + ((size_t)(C * 4 + o2) * 256 + R * 32 + jl) * 8 + k0) = pk;
    }
}

// ---------------------------------------------------------------------------
// Pairwise L1-exp2 v4: SYMMETRIC circulant — each unordered pair computed
// once, credited to both sides via ds_bpermute. Thread (jg=t&63, q=t>>6):
// j = jg + 64a (a=0..3), d in [8q+1, 8q+8]; pair (j, (j+d)&255).
//   own:     acc[a] += e[a]
//   partner: receiver r=(jg+dd)&63 gets sender's e's; rot=(d>>6)+(r<dd);
//            acc[c] += eRecv[(c-rot)&3].    d==128: own-only (a and a+2
//            compute the two orientations). Diagonal never computed -> no -1.
// All register accumulation in fixed order: deterministic.
// ---------------------------------------------------------------------------
__global__ __launch_bounds__(1024)
void k_pair(const u16* __restrict__ Mh, float* __restrict__ out) {
    __shared__ __align__(16) uint4 Msh[BATCH];    // 4 KB
    __shared__ float Ps[16][256];                 // 16 KB
    const int o = blockIdx.x, t = threadIdx.x;

    if (t < 256) Msh[t] = ((const uint4*)(Mh + (size_t)o * 2048))[t];
    __syncthreads();

    const int jg = t & 63, q = t >> 6;
    h16x2 m[4][4];
#pragma unroll
    for (int c = 0; c < 4; ++c) {
        uint4 mm = Msh[jg + 64 * c];
        m[c][0] = __builtin_bit_cast(h16x2, mm.x);
        m[c][1] = __builtin_bit_cast(h16x2, mm.y);
        m[c][2] = __builtin_bit_cast(h16x2, mm.z);
        m[c][3] = __builtin_bit_cast(h16x2, mm.w);
    }

    float acc[4] = {0.f, 0.f, 0.f, 0.f};
    const int dbase = q * 8 + 1;                  // q=15 -> d 121..128
#pragma unroll
    for (int ii = 0; ii < 8; ++ii) {
        const int d  = dbase + ii;
        const int dd = d & 63;
        const int dl = d >> 6;                    // 0,1 (2 only at d=128)
        float e[4];
#pragma unroll
        for (int c = 0; c < 4; ++c) {
            uint4 uu = Msh[(jg + 64 * c + d) & 255];
            h16x2 d0 = __builtin_bit_cast(h16x2, uu.x) - m[c][0];
            h16x2 d1 = __builtin_bit_cast(h16x2, uu.y) - m[c][1];
            h16x2 d2 = __builtin_bit_cast(h16x2, uu.z) - m[c][2];
            h16x2 d3 = __builtin_bit_cast(h16x2, uu.w) - m[c][3];
            h16x2 e0 = __builtin_bit_cast(h16x2, __builtin_bit_cast(u32, d0) & 0x7fff7fffu);
            h16x2 e1 = __builtin_bit_cast(h16x2, __builtin_bit_cast(u32, d1) & 0x7fff7fffu);
            h16x2 e2 = __builtin_bit_cast(h16x2, __builtin_bit_cast(u32, d2) & 0x7fff7fffu);
            h16x2 e3 = __builtin_bit_cast(h16x2, __builtin_bit_cast(u32, d3) & 0x7fff7fffu);
            h16x2 s = (e0 + e1) + (e2 + e3);
            float ev = exp2_fast(hsum_neg(s));
            e[c] = ev;
            acc[c] += ev;
        }
        if (d != 128) {                           // wave-uniform branch
            const int src = (jg - dd) & 63;
            float r0 = bperm(src, e[0]);
            float r1 = bperm(src, e[1]);
            float r2 = bperm(src, e[2]);
            float r3 = bperm(src, e[3]);
            const int rot = dl + (jg < dd ? 1 : 0);   // 0..2
            acc[0] += rot == 0 ? r0 : (rot == 1 ? r3 : r2);
            acc[1] += rot == 0 ? r1 : (rot == 1 ? r0 : r3);
            acc[2] += rot == 0 ? r2 : (rot == 1 ? r1 : r0);
            acc[3] += rot == 0 ? r3 : (rot == 1 ? r2 : r1);
        }
    }
#pragma unroll
    for (int c = 0; c < 4; ++c) Ps[q][jg + 64 * c] = acc[c];
    __syncthreads();

    if (t < 256) {
        float s = 0.f;
#pragma unroll
        for (int q2 = 0; q2 < 16; ++q2) s += Ps[q2][t];
        out[(size_t)t * OSTRIDE + IN_F + o] = s;  // diagonal excluded: no -1
    }
}

extern "C" void kernel_launch(void* const* d_in, const int* in_sizes, int n_in,
                              void* d_out, int out_size, void* d_ws, size_t ws_size,
                              hipStream_t stream) {
    const float* x = (const float*)d_in[0];   // [256, 2048]
    const float* T = (const float*)d_in[1];   // [2048][2048] flattened
    float* out = (float*)d_out;               // [256, 2304]
    char* ws = (char*)d_ws;
    u16* Mh = (u16*)ws;
    u16* Wt = (u16*)(ws + WT_BASE);
    u16* Xb = (u16*)(ws + XB_BASE);

    k_prep<<<384, 256, 0, stream>>>(x, T, Wt, Xb, out);
    k_gemm<<<512, 512, 0, stream>>>(Xb, Wt, Mh);
    k_pair<<<256, 1024, 0, stream>>>(Mh, out);
}

// Round 15
// 26.203 us; speedup vs baseline: 10.5367x; 1.0711x over previous
//
#include <hip/hip_runtime.h>
#include <math.h>

#define BATCH   256
#define IN_F    2048
#define OUT_F   256
#define NCOL    2048    /* OUT_F*KD */
#define OSTRIDE 2304    /* IN_F + OUT_F */
#define LOG2E   1.4426950408889634f

typedef float    f32x4  __attribute__((ext_vector_type(4)));
typedef short    bf16x8 __attribute__((ext_vector_type(8)));
typedef _Float16 h16x2  __attribute__((ext_vector_type(2)));
typedef __fp16   fp16x2 __attribute__((ext_vector_type(2)));
typedef unsigned short u16;
typedef unsigned int   u32;

// ws layout:
//   [0, 1MB)   Mh f16 [256 o][256 j][8 k]
//   [16,24MB)  Wt bf16 tiled [nt(128)][kchunk(256)][n16(16)][8]
//   [64,65MB)  Xb bf16 tiled [rt(16)][kchunk(256)][r16(16)][8] (pre *log2e)
#define WT_BASE   (16u << 20)
#define XB_BASE   (64u << 20)

__device__ __forceinline__ u16 f2bf(float f) {
    unsigned u = __builtin_bit_cast(unsigned, f);
    u += 0x7fff + ((u >> 16) & 1);              // RNE
    return (u16)(u >> 16);
}

__device__ __forceinline__ float exp2_fast(float x) {
#if __has_builtin(__builtin_amdgcn_exp2f)
    return __builtin_amdgcn_exp2f(x);
#else
    float r; asm("v_exp_f32 %0, %1" : "=v"(r) : "v"(x)); return r;
#endif
}

__device__ __forceinline__ float hsum_neg(h16x2 s) {
#if __has_builtin(__builtin_amdgcn_fdot2)
    const h16x2 n1 = {(_Float16)-1.0f, (_Float16)-1.0f};
    return __builtin_amdgcn_fdot2(s, n1, 0.0f, false);
#else
    return -((float)s[0] + (float)s[1]);
#endif
}

__device__ __forceinline__ float bperm(int srcLane, float v) {
    return __builtin_bit_cast(float,
        __builtin_amdgcn_ds_bpermute(srcLane * 4, __builtin_bit_cast(int, v)));
}

// ---------------------------------------------------------------------------
// Prep. tconv blocks 0..127 XCD-ALIGNED with gemm consumers: block b writes
// only C-panels with C%8 == b%8 (gemm block bid%8 == C%8 reads them on the
// same XCD -> dirty lines stay in local L2). xconv blocks 128..383 unchanged.
// ---------------------------------------------------------------------------
__global__ __launch_bounds__(256)
void k_prep(const float* __restrict__ X, const float* __restrict__ T,
            u16* __restrict__ Wt, u16* __restrict__ Xb,
            float* __restrict__ out) {
    const int b = blockIdx.x, t = threadIdx.x;
    if (b < 128) {
        const int c8 = b & 7;                  // XCD group
        const int kg = b >> 3;                 // 128-k group (0..15)
        const int p  = t & 127;                // col-pair index
        const int C  = c8 + 8 * (p >> 4);      // C-panel (C%8 == c8)
        const int n  = C * 32 + (p & 15) * 2;  // even column
        const int kh = (t >> 7) * 64;          // k-half within group
        const int nt = n >> 4, n16 = n & 15;
#pragma unroll
        for (int kc = 0; kc < 8; ++kc) {
            const int kb = kg * 128 + kh + kc * 8;
            u16 h0[8], h1[8];
#pragma unroll
            for (int r = 0; r < 8; ++r) {
                float2 v = *(const float2*)(T + (size_t)(kb + r) * NCOL + n);
                h0[r] = f2bf(v.x);
                h1[r] = f2bf(v.y);
            }
            u16* dst = Wt + ((size_t)(nt * 256 + (kb >> 3)) * 16 + n16) * 8;
            *(float4*)dst       = *(float4*)h0;
            *(float4*)(dst + 8) = *(float4*)h1;
        }
    } else {
        const int g   = b - 128;
        const int rt  = g >> 4;
        const int kc  = (g & 15) * 16 + (t & 15);
        const int r16 = t >> 4;
        const int row = rt * 16 + r16;
        const float* src = X + (size_t)row * IN_F + kc * 8;
        float4 v0 = *(const float4*)src;
        float4 v1 = *(const float4*)(src + 4);
        u16 h[8] = {f2bf(v0.x * LOG2E), f2bf(v0.y * LOG2E),
                    f2bf(v0.z * LOG2E), f2bf(v0.w * LOG2E),
                    f2bf(v1.x * LOG2E), f2bf(v1.y * LOG2E),
                    f2bf(v1.z * LOG2E), f2bf(v1.w * LOG2E)};
        *(float4*)(Xb + ((size_t)(rt * 256 + kc) * 16 + r16) * 8) = *(float4*)h;
        float* od = out + (size_t)row * OSTRIDE + kc * 8;
        *(float4*)od       = v0;
        *(float4*)(od + 4) = v1;
    }
}

// ---------------------------------------------------------------------------
// MFMA GEMM (8-way in-block split-K). 512 blocks x 8 waves, 2 blocks/CU.
// bid%8 = C%8: same XCD as the tconv writer of its Wt panel.
// (identical to R12/R14)
// ---------------------------------------------------------------------------
__global__ __launch_bounds__(512, 4)
void k_gemm(const u16* __restrict__ Xb, const u16* __restrict__ Wt,
            u16* __restrict__ Mh) {
    __shared__ float L[8][32][33];     // 33.8 KB
    const int t = threadIdx.x, l = t & 63, kcw = t >> 6;
    const int bid = blockIdx.x;
    const int R = bid >> 6;            // 0..7
    const int C = bid & 63;            // 0..63

    const int lo = (l >> 4) * 128 + (l & 15) * 8;
    const u16* ap0 = Xb + (size_t)(R * 2) * 32768 + kcw * 4096 + lo;
    const u16* ap1 = ap0 + 32768;
    const u16* bp0 = Wt + (size_t)(C * 2) * 32768 + kcw * 4096 + lo;
    const u16* bp1 = bp0 + 32768;

    f32x4 c00 = {0.f,0.f,0.f,0.f}, c01 = {0.f,0.f,0.f,0.f};
    f32x4 c10 = {0.f,0.f,0.f,0.f}, c11 = {0.f,0.f,0.f,0.f};

#pragma unroll 8
    for (int s = 0; s < 8; ++s) {
        bf16x8 a0 = *(const bf16x8*)(ap0 + s * 512);
        bf16x8 a1 = *(const bf16x8*)(ap1 + s * 512);
        bf16x8 b0 = *(const bf16x8*)(bp0 + s * 512);
        bf16x8 b1 = *(const bf16x8*)(bp1 + s * 512);
        c00 = __builtin_amdgcn_mfma_f32_16x16x32_bf16(a0, b0, c00, 0, 0, 0);
        c01 = __builtin_amdgcn_mfma_f32_16x16x32_bf16(a0, b1, c01, 0, 0, 0);
        c10 = __builtin_amdgcn_mfma_f32_16x16x32_bf16(a1, b0, c10, 0, 0, 0);
        c11 = __builtin_amdgcn_mfma_f32_16x16x32_bf16(a1, b1, c11, 0, 0, 0);
    }

    const int lq = l >> 4, lm = l & 15;
#define PUT(acc, qi, qj) do { \
        _Pragma("unroll") \
        for (int r = 0; r < 4; ++r) \
            L[kcw][(qj) * 16 + lm][(qi) * 16 + lq * 4 + r] = acc[r]; \
    } while (0)
    PUT(c00, 0, 0); PUT(c01, 0, 1); PUT(c10, 1, 0); PUT(c11, 1, 1);
#undef PUT
    __syncthreads();

    if (t < 256) {
        const int o2 = t >> 6;             // 0..3
        const int jl = (t & 63) >> 1;      // 0..31
        const int k0 = (t & 1) * 4;        // 0 or 4
        float v[4];
#pragma unroll
        for (int i = 0; i < 4; ++i) {
            const int c = o2 * 8 + k0 + i;
            float s0 = (L[0][c][jl] + L[1][c][jl]) + (L[2][c][jl] + L[3][c][jl]);
            float s1 = (L[4][c][jl] + L[5][c][jl]) + (L[6][c][jl] + L[7][c][jl]);
            v[i] = s0 + s1;
        }
        fp16x2 p0 = __builtin_amdgcn_cvt_pkrtz(v[0], v[1]);
        fp16x2 p1 = __builtin_amdgcn_cvt_pkrtz(v[2], v[3]);
        uint2 pk = {__builtin_bit_cast(u32, p0), __builtin_bit_cast(u32, p1)};
        *(uint2*)(Mh + ((size_t)(C * 4 + o2) * 256 + R * 32 + jl) * 8 + k0) = pk;
    }
}

// ---------------------------------------------------------------------------
// Pairwise L1-exp2 v4 (symmetric circulant), with XCD-ALIGNED o mapping:
// o chosen so bid%8 == (o>>2)%8 == writing gemm block's XCD.
// ---------------------------------------------------------------------------
__global__ __launch_bounds__(1024)
void k_pair(const u16* __restrict__ Mh, float* __restrict__ out) {
    __shared__ __align__(16) uint4 Msh[BATCH];    // 4 KB
    __shared__ float Ps[16][256];                 // 16 KB
    const int t = threadIdx.x;
    const int g = blockIdx.x & 7, idx = blockIdx.x >> 3;
    const int o = (g + 8 * (idx >> 2)) * 4 + (idx & 3);   // (o>>2)%8 == g

    if (t < 256) Msh[t] = ((const uint4*)(Mh + (size_t)o * 2048))[t];
    __syncthreads();

    const int jg = t & 63, q = t >> 6;
    h16x2 m[4][4];
#pragma unroll
    for (int c = 0; c < 4; ++c) {
        uint4 mm = Msh[jg + 64 * c];
        m[c][0] = __builtin_bit_cast(h16x2, mm.x);
        m[c][1] = __builtin_bit_cast(h16x2, mm.y);
        m[c][2] = __builtin_bit_cast(h16x2, mm.z);
        m[c][3] = __builtin_bit_cast(h16x2, mm.w);
    }

    float acc[4] = {0.f, 0.f, 0.f, 0.f};
    const int dbase = q * 8 + 1;
#pragma unroll
    for (int ii = 0; ii < 8; ++ii) {
        const int d  = dbase + ii;
        const int dd = d & 63;
        const int dl = d >> 6;
        float e[4];
#pragma unroll
        for (int c = 0; c < 4; ++c) {
            uint4 uu = Msh[(jg + 64 * c + d) & 255];
            h16x2 d0 = __builtin_bit_cast(h16x2, uu.x) - m[c][0];
            h16x2 d1 = __builtin_bit_cast(h16x2, uu.y) - m[c][1];
            h16x2 d2 = __builtin_bit_cast(h16x2, uu.z) - m[c][2];
            h16x2 d3 = __builtin_bit_cast(h16x2, uu.w) - m[c][3];
            h16x2 e0 = __builtin_bit_cast(h16x2, __builtin_bit_cast(u32, d0) & 0x7fff7fffu);
            h16x2 e1 = __builtin_bit_cast(h16x2, __builtin_bit_cast(u32, d1) & 0x7fff7fffu);
            h16x2 e2 = __builtin_bit_cast(h16x2, __builtin_bit_cast(u32, d2) & 0x7fff7fffu);
            h16x2 e3 = __builtin_bit_cast(h16x2, __builtin_bit_cast(u32, d3) & 0x7fff7fffu);
            h16x2 s = (e0 + e1) + (e2 + e3);
            float ev = exp2_fast(hsum_neg(s));
            e[c] = ev;
            acc[c] += ev;
        }
        if (d != 128) {
            const int src = (jg - dd) & 63;
            float r0 = bperm(src, e[0]);
            float r1 = bperm(src, e[1]);
            float r2 = bperm(src, e[2]);
            float r3 = bperm(src, e[3]);
            const int rot = dl + (jg < dd ? 1 : 0);
            acc[0] += rot == 0 ? r0 : (rot == 1 ? r3 : r2);
            acc[1] += rot == 0 ? r1 : (rot == 1 ? r0 : r3);
            acc[2] += rot == 0 ? r2 : (rot == 1 ? r1 : r0);
            acc[3] += rot == 0 ? r3 : (rot == 1 ? r2 : r1);
        }
    }
#pragma unroll
    for (int c = 0; c < 4; ++c) Ps[q][jg + 64 * c] = acc[c];
    __syncthreads();

    if (t < 256) {
        float s = 0.f;
#pragma unroll
        for (int q2 = 0; q2 < 16; ++q2) s += Ps[q2][t];
        out[(size_t)t * OSTRIDE + IN_F + o] = s;
    }
}

extern "C" void kernel_launch(void* const* d_in, const int* in_sizes, int n_in,
                              void* d_out, int out_size, void* d_ws, size_t ws_size,
                              hipStream_t stream) {
    const float* x = (const float*)d_in[0];   // [256, 2048]
    const float* T = (const float*)d_in[1];   // [2048][2048] flattened
    float* out = (float*)d_out;               // [256, 2304]
    char* ws = (char*)d_ws;
    u16* Mh = (u16*)ws;
    u16* Wt = (u16*)(ws + WT_BASE);
    u16* Xb = (u16*)(ws + XB_BASE);

    k_prep<<<384, 256, 0, stream>>>(x, T, Wt, Xb, out);
    k_gemm<<<512, 512, 0, stream>>>(Xb, Wt, Mh);
    k_pair<<<256, 1024, 0, stream>>>(Mh, out);
}